// Round 3
// baseline (3872.845 us; speedup 1.0000x reference)
//
#include <hip/hip_runtime.h>
#include <hip/hip_bf16.h>
#include <math.h>

typedef unsigned short u16;
typedef unsigned int   u32;
using short8  = __attribute__((ext_vector_type(8))) short;
using f32x4   = __attribute__((ext_vector_type(4))) float;

static constexpr int NNODE = 50000;
static constexpr int NEDGE = 600000;
static constexpr float EPSC   = 0.1f;
static constexpr float GAMMAC = 0.1f;

static constexpr int NBLK  = 1024;                 // 256 CU x 4 blocks/CU (co-resident)
static constexpr int NTILE = (NNODE + 63) / 64;    // 782 GEMM row-tiles
static constexpr int DEGB  = NBLK - NTILE;         // 242 deg-count blocks in phase B

// ---- workspace layout (float-index offsets) ----
static constexpr long long O_DINV   = 0;                         // float 50000
static constexpr long long O_DEGI   = 50000;                     // int 50000
static constexpr long long O_ROWPTR = 100000;                    // int 50000
static constexpr long long O_CURSOR = 150004;                    // int 50000
static constexpr long long O_GCUR   = 200052;                    // int 1
static constexpr long long O_ECSR   = 200260;                    // int2 600000
// bf16 weights
static constexpr long long O_WHB    = 1400260;                   // 32768 bf16
static constexpr long long O_G1TB   = O_WHB  + 16384;
static constexpr long long O_AW1B   = O_G1TB + 8192;
static constexpr long long O_W2B    = O_AW1B + 8192;
static constexpr long long O_AW2B   = O_W2B  + 4096;
static constexpr long long O_G2TB   = O_AW2B + 2048;
static constexpr long long O_WFCB   = O_G2TB + 2048;
// big buffers
static constexpr long long O_AGGB   = 3450004;                   // bf16 6.4M
static constexpr long long O_HB0    = O_AGGB + 3200000;          // bf16 6.4M
static constexpr long long O_HB1    = O_HB0  + 3200000;          // bf16 6.4M
static constexpr long long O_S0     = O_HB1  + 3200000;          // fp8 6.4M
static constexpr long long O_S1     = O_S0   + 1600000;          // fp8 6.4M

__device__ __forceinline__ float bf2f(u16 u) {
    return __uint_as_float(((unsigned)u) << 16);
}
__device__ __forceinline__ u16 f2bf(float f) {
    unsigned u = __float_as_uint(f);
    return (u16)((u + 0x7FFFu + ((u >> 16) & 1u)) >> 16);
}
__device__ __forceinline__ float ftanh(float x) {
    float x2 = fminf(fmaxf(2.f * x, -30.f), 30.f);
    float e = __expf(x2);
    return (e - 1.f) * __builtin_amdgcn_rcpf(e + 1.f);
}
__device__ __forceinline__ u16 pk_fp8(float a, float b) {
    int pk = __builtin_amdgcn_cvt_pk_fp8_f32(a, b, 0, false);
    return (u16)(pk & 0xffff);
}
__device__ __forceinline__ void acc_fp8x4(float* a, u32 v, float w) {
    a[0] += __builtin_amdgcn_cvt_f32_fp8(v, 0) * w;
    a[1] += __builtin_amdgcn_cvt_f32_fp8(v, 1) * w;
    a[2] += __builtin_amdgcn_cvt_f32_fp8(v, 2) * w;
    a[3] += __builtin_amdgcn_cvt_f32_fp8(v, 3) * w;
}

// ---- device-scope grid barrier (state in device globals, NOT poisoned ws) ----
// sense-reversing via monotone generation: survives hipGraph replays (bar ends 0).
__device__ int g_bar = 0;
__device__ int g_gen = 0;

__device__ __forceinline__ void gridsync() {
    __threadfence();                   // release: drain + write back caches
    __syncthreads();
    if (threadIdx.x == 0) {
        int g = __hip_atomic_load(&g_gen, __ATOMIC_RELAXED, __HIP_MEMORY_SCOPE_AGENT);
        if (__hip_atomic_fetch_add(&g_bar, 1, __ATOMIC_ACQ_REL, __HIP_MEMORY_SCOPE_AGENT)
            == (int)gridDim.x - 1) {
            __hip_atomic_store(&g_bar, 0, __ATOMIC_RELAXED, __HIP_MEMORY_SCOPE_AGENT);
            __hip_atomic_store(&g_gen, g + 1, __ATOMIC_RELEASE, __HIP_MEMORY_SCOPE_AGENT);
        } else {
            while (__hip_atomic_load(&g_gen, __ATOMIC_ACQUIRE, __HIP_MEMORY_SCOPE_AGENT) == g)
                __builtin_amdgcn_s_sleep(2);
        }
    }
    __syncthreads();
    __threadfence();                   // acquire: invalidate stale lines
}

// ---- phase: x @ w_hid^T -> leaky -> hB0 + fp8 shadow (one 64-row tile/block) ----
__device__ __forceinline__ void ph_mgemm_x(char* smem, const float* __restrict__ x,
        const u16* __restrict__ Bt, const float* __restrict__ bias,
        u16* __restrict__ outB, u16* __restrict__ outB8) {
    constexpr int K = 256, KCHU = 128, KC = 4, P = 136, CW = 129;
    u16*   bl   = (u16*)smem;
    float* accL = (float*)smem;
    const int wave = threadIdx.x >> 6, lane = threadIdx.x & 63;
    const int m = lane & 15, q = lane >> 4;
    const int rowbase = blockIdx.x * 64 + wave * 16;
    const int row = rowbase + m;
    const bool rok = row < NNODE;
    const short8 z8 = {0,0,0,0,0,0,0,0};

    short8 af[8];
    {
        const float* apf = x + (long long)row * K;
        #pragma unroll
        for (int k = 0; k < 8; ++k) {
            short8 t = z8;
            if (rok) {
                const float4* p = (const float4*)(apf + (k * 4 + q) * 8);
                float4 a = p[0], b = p[1];
                t[0]=(short)f2bf(a.x); t[1]=(short)f2bf(a.y); t[2]=(short)f2bf(a.z); t[3]=(short)f2bf(a.w);
                t[4]=(short)f2bf(b.x); t[5]=(short)f2bf(b.y); t[6]=(short)f2bf(b.z); t[7]=(short)f2bf(b.w);
            }
            af[k] = t;
        }
    }

    f32x4 acc[8];
    #pragma unroll
    for (int j = 0; j < 8; ++j) acc[j] = (f32x4){0.f,0.f,0.f,0.f};

    for (int ch = 0; ch < 2; ++ch) {
        if (ch) __syncthreads();
        for (int t = threadIdx.x; t < 2048; t += 256) {
            int r = t >> 4, c = t & 15;
            *(short8*)&bl[r * P + c * 8] = *(const short8*)&Bt[(long long)r * K + ch * KCHU + c * 8];
        }
        __syncthreads();
        #pragma unroll
        for (int j = 0; j < 8; ++j)
            #pragma unroll
            for (int k = 0; k < KC; ++k) {
                short8 bf_ = *(const short8*)&bl[(j * 16 + m) * P + k * 32 + q * 8];
                acc[j] = __builtin_amdgcn_mfma_f32_16x16x32_bf16(af[ch * KC + k], bf_, acc[j], 0, 0, 0);
            }
    }

    __syncthreads();
    #pragma unroll
    for (int j = 0; j < 8; ++j)
        #pragma unroll
        for (int r = 0; r < 4; ++r)
            accL[(wave * 16 + q * 4 + r) * CW + j * 16 + m] = acc[j][r];
    __syncthreads();

    const int c0 = lane * 2;
    float2 bv = {bias[c0], bias[c0 + 1]};
    #pragma unroll
    for (int rl = 0; rl < 16; ++rl) {
        int rowD = rowbase + rl;
        if (rowD >= NNODE) continue;
        float2 v = *(const float2*)&accL[(wave * 16 + rl) * CW + c0];
        v.x += bv.x; v.y += bv.y;
        v.x = v.x > 0.f ? v.x : 0.01f * v.x;
        v.y = v.y > 0.f ? v.y : 0.01f * v.y;
        long long o = (long long)rowD * 128 + c0;
        ushort2 ob; ob.x = f2bf(v.x); ob.y = f2bf(v.y);
        *(ushort2*)&outB[o] = ob;
        outB8[o >> 1] = pk_fp8(v.x, v.y);
    }
}

// ---- phase: CSR gather (fp8 in, bf16 out), grid-strided wave-per-node ----
template<int HD>
__device__ __forceinline__ void ph_gather(const int* __restrict__ rowptr,
        const int* __restrict__ degi, const int2* __restrict__ ecsr,
        const float* __restrict__ dinv, const u32* __restrict__ g8,
        u16* __restrict__ aggB) {
    const int lane = threadIdx.x & 63;
    const int qr = lane >> 4, l4 = lane & 15;
    constexpr int EL = (HD == 128) ? 8 : 4;
    for (int node = blockIdx.x * 4 + (threadIdx.x >> 6); node < NNODE; node += NBLK * 4) {
        const int r0 = rowptr[node];
        const int r1 = r0 + degi[node];
        const float wself = dinv[node] * dinv[node];
        float a[EL];
        #pragma unroll
        for (int i = 0; i < EL; ++i) a[i] = 0.f;
        if (qr == 0) {
            if (HD == 128) {
                uint2 gv = ((const uint2*)g8)[(long long)node * 16 + l4];
                acc_fp8x4(a, gv.x, wself);
                acc_fp8x4(a + 4, gv.y, wself);
            } else {
                u32 gv = g8[(long long)node * 16 + l4];
                acc_fp8x4(a, gv, wself);
            }
        }
        for (int base = r0; base < r1; base += 64) {
            int idx = base + lane;
            int cs = 0; float cw = 0.f;
            if (idx < r1) { int2 ev = ecsr[idx]; cs = ev.x; cw = __int_as_float(ev.y); }
            int cnt = min(64, r1 - base);
            // 4 rounds (16 edges) per step: padded with zero-weight lanes -> 4 loads in flight
            for (int j = 0; j < cnt; j += 16) {
                #pragma unroll
                for (int u = 0; u < 4; ++u) {
                    int jj = j + u * 4 + qr;
                    int   s = __shfl(cs, jj);
                    float w = __shfl(cw, jj);
                    if (HD == 128) {
                        uint2 gv = ((const uint2*)g8)[(long long)s * 16 + l4];
                        acc_fp8x4(a, gv.x, w);
                        acc_fp8x4(a + 4, gv.y, w);
                    } else {
                        u32 gv = g8[(long long)s * 16 + l4];
                        acc_fp8x4(a, gv, w);
                    }
                }
            }
        }
        #pragma unroll
        for (int i = 0; i < EL; ++i) {
            a[i] += __shfl_xor(a[i], 16);
            a[i] += __shfl_xor(a[i], 32);
        }
        if (HD == 128) {
            float v0 = (qr == 0) ? a[0] : (qr == 1) ? a[2] : (qr == 2) ? a[4] : a[6];
            float v1 = (qr == 0) ? a[1] : (qr == 1) ? a[3] : (qr == 2) ? a[5] : a[7];
            long long o = (long long)node * 128 + l4 * 8 + qr * 2;
            ushort2 ob; ob.x = f2bf(v0); ob.y = f2bf(v1);
            *(ushort2*)&aggB[o] = ob;
        } else {
            float v = (qr == 0) ? a[0] : (qr == 1) ? a[1] : (qr == 2) ? a[2] : a[3];
            aggB[(long long)node * 64 + l4 * 4 + qr] = f2bf(v);
        }
    }
}

// ---- phase: conv1 step GEMM (+optional fused h2 GEMM), one 64-row tile/block ----
template<int TAIL>
__device__ __forceinline__ void ph_conv1(char* smem, const u16* __restrict__ hA,
        const u16* __restrict__ gA, const u16* __restrict__ BtW, const u16* __restrict__ BtG,
        const float* __restrict__ bias, u16* __restrict__ outB, u16* __restrict__ outB8,
        const u16* __restrict__ w2W, const float* __restrict__ b2) {
    constexpr int K = 128, KS = 4, P = 136, CW = 129;
    u16*   bl   = (u16*)smem;
    float* accL = (float*)smem;
    const int wave = threadIdx.x >> 6, lane = threadIdx.x & 63;
    const int m = lane & 15, q = lane >> 4;
    const int rowbase = blockIdx.x * 64 + wave * 16;
    const int row = rowbase + m;
    const bool rok = row < NNODE;
    const short8 z8 = {0,0,0,0,0,0,0,0};

    short8 af1[KS], af2[KS];
    {
        const short8* ap1 = (const short8*)(hA + (long long)row * K);
        const short8* ap2 = (const short8*)(gA + (long long)row * K);
        #pragma unroll
        for (int k = 0; k < KS; ++k) {
            af1[k] = rok ? ap1[k * 4 + q] : z8;
            af2[k] = rok ? ap2[k * 4 + q] : z8;
        }
    }

    f32x4 acc[8];
    #pragma unroll
    for (int j = 0; j < 8; ++j) acc[j] = (f32x4){0.f,0.f,0.f,0.f};

    #pragma unroll
    for (int pass = 0; pass < 2; ++pass) {
        const u16* Bcur = pass ? BtG : BtW;
        if (pass) __syncthreads();
        for (int t = threadIdx.x; t < 2048; t += 256) {
            int r = t >> 4, c = t & 15;
            *(short8*)&bl[r * P + c * 8] = *(const short8*)&Bcur[(long long)r * K + c * 8];
        }
        __syncthreads();
        #pragma unroll
        for (int j = 0; j < 8; ++j)
            #pragma unroll
            for (int k = 0; k < KS; ++k) {
                short8 bf_ = *(const short8*)&bl[(j * 16 + m) * P + k * 32 + q * 8];
                acc[j] = __builtin_amdgcn_mfma_f32_16x16x32_bf16(
                    pass ? af2[k] : af1[k], bf_, acc[j], 0, 0, 0);
            }
    }

    __syncthreads();
    #pragma unroll
    for (int j = 0; j < 8; ++j)
        #pragma unroll
        for (int r = 0; r < 4; ++r)
            accL[(wave * 16 + q * 4 + r) * CW + j * 16 + m] = acc[j][r];
    __syncthreads();

    const int c0 = lane * 2;
    if (TAIL == 0) {
        float2 bv = {bias[c0], bias[c0 + 1]};
        #pragma unroll
        for (int rl = 0; rl < 16; ++rl) {
            int rowD = rowbase + rl;
            if (rowD >= NNODE) continue;
            float2 v = *(const float2*)&accL[(wave * 16 + rl) * CW + c0];
            long long o = (long long)rowD * K + c0;
            ushort2 hh = *(const ushort2*)&hA[o];
            float n0 = bf2f(hh.x) + EPSC * ftanh(v.x + bv.x);
            float n1 = bf2f(hh.y) + EPSC * ftanh(v.y + bv.y);
            ushort2 ob; ob.x = f2bf(n0); ob.y = f2bf(n1);
            *(ushort2*)&outB[o] = ob;
            outB8[o >> 1] = pk_fp8(n0, n1);
        }
        return;
    }

    // TAIL: leaky(h_new) into regs, then LDS tile [0,17408) + w2 [17408,34816)
    u32 hv[16];
    {
        float2 bv = {bias[c0], bias[c0 + 1]};
        #pragma unroll
        for (int rl = 0; rl < 16; ++rl) {
            int rowD = rowbase + rl;
            float n0 = 0.f, n1 = 0.f;
            if (rowD < NNODE) {
                float2 v = *(const float2*)&accL[(wave * 16 + rl) * CW + c0];
                long long o = (long long)rowD * K + c0;
                ushort2 hh = *(const ushort2*)&hA[o];
                n0 = bf2f(hh.x) + EPSC * ftanh(v.x + bv.x);
                n1 = bf2f(hh.y) + EPSC * ftanh(v.y + bv.y);
                n0 = n0 > 0.f ? n0 : 0.01f * n0;
                n1 = n1 > 0.f ? n1 : 0.01f * n1;
            }
            hv[rl] = (u32)f2bf(n0) | ((u32)f2bf(n1) << 16);
        }
    }
    __syncthreads();   // everyone done reading accL; smem repurposed

    u16* aggT = (u16*)smem;            // [64][136] bf16, 17408 B
    u16* bl2  = (u16*)(smem + 17408);  // w2 [64][136] bf16, 17408 B
    #pragma unroll
    for (int rl = 0; rl < 16; ++rl)
        *(u32*)&aggT[(wave * 16 + rl) * P + c0] = hv[rl];
    for (int t = threadIdx.x; t < 1024; t += 256) {
        int r = t >> 4, c = t & 15;
        *(short8*)&bl2[r * P + c * 8] = *(const short8*)&w2W[(long long)r * K + c * 8];
    }
    __syncthreads();

    short8 af3[4];
    #pragma unroll
    for (int k = 0; k < 4; ++k)
        af3[k] = *(const short8*)&aggT[(wave * 16 + m) * P + k * 32 + q * 8];

    f32x4 acc2[4];
    #pragma unroll
    for (int j = 0; j < 4; ++j) acc2[j] = (f32x4){0.f,0.f,0.f,0.f};
    #pragma unroll
    for (int j = 0; j < 4; ++j)
        #pragma unroll
        for (int k = 0; k < 4; ++k) {
            short8 bf_ = *(const short8*)&bl2[(j * 16 + m) * P + k * 32 + q * 8];
            acc2[j] = __builtin_amdgcn_mfma_f32_16x16x32_bf16(af3[k], bf_, acc2[j], 0, 0, 0);
        }

    __syncthreads();
    constexpr int CW2 = 65;
    float* accL2 = (float*)smem;       // 16640 B, overwrites aggT (af3 already in regs)
    #pragma unroll
    for (int j = 0; j < 4; ++j)
        #pragma unroll
        for (int r = 0; r < 4; ++r)
            accL2[(wave * 16 + q * 4 + r) * CW2 + j * 16 + m] = acc2[j][r];
    __syncthreads();

    if (c0 < 64) {
        float2 bv = {b2[c0], b2[c0 + 1]};
        #pragma unroll
        for (int rl = 0; rl < 16; ++rl) {
            int rowD = rowbase + rl;
            if (rowD >= NNODE) continue;
            float2 v = *(const float2*)&accL2[(wave * 16 + rl) * CW2 + c0];
            v.x += bv.x; v.y += bv.y;
            v.x = v.x > 0.f ? v.x : 0.01f * v.x;
            v.y = v.y > 0.f ? v.y : 0.01f * v.y;
            long long o = (long long)rowD * 64 + c0;
            ushort2 ob; ob.x = f2bf(v.x); ob.y = f2bf(v.y);
            *(ushort2*)&outB[o] = ob;
            outB8[o >> 1] = pk_fp8(v.x, v.y);
        }
    }
}

// ---- phase: conv2 + FC + log_softmax, one 64-row tile/block ----
__device__ __forceinline__ void ph_conv2fc(char* smem, const u16* __restrict__ hA,
        const u16* __restrict__ gA, const u16* __restrict__ BtW, const u16* __restrict__ BtG,
        const float* __restrict__ bias, const u16* __restrict__ wfcB,
        const float* __restrict__ bfc, float* __restrict__ outF) {
    constexpr int K = 64, NT = 4, KS = 2, P = 72, CW = 65;
    constexpr int R1 = 64 * CW * 4;    // 16640
    u16*   bl   = (u16*)smem;
    float* accL = (float*)smem;
    u16*   aggT = (u16*)(smem + R1);   // [64][72] bf16, 9216 B
    const int wave = threadIdx.x >> 6, lane = threadIdx.x & 63;
    const int m = lane & 15, q = lane >> 4;
    const int rowbase = blockIdx.x * 64 + wave * 16;
    const int row = rowbase + m;
    const bool rok = row < NNODE;
    const short8 z8 = {0,0,0,0,0,0,0,0};

    short8 af1[KS], af2[KS];
    {
        const short8* ap1 = (const short8*)(hA + (long long)row * K);
        const short8* ap2 = (const short8*)(gA + (long long)row * K);
        #pragma unroll
        for (int k = 0; k < KS; ++k) {
            af1[k] = rok ? ap1[k * 4 + q] : z8;
            af2[k] = rok ? ap2[k * 4 + q] : z8;
        }
    }

    f32x4 acc[NT];
    #pragma unroll
    for (int j = 0; j < NT; ++j) acc[j] = (f32x4){0.f,0.f,0.f,0.f};

    #pragma unroll
    for (int pass = 0; pass < 2; ++pass) {
        const u16* Bcur = pass ? BtG : BtW;
        if (pass) __syncthreads();
        for (int t = threadIdx.x; t < 512; t += 256) {
            int r = t >> 3, c = t & 7;
            *(short8*)&bl[r * P + c * 8] = *(const short8*)&Bcur[(long long)r * K + c * 8];
        }
        __syncthreads();
        #pragma unroll
        for (int j = 0; j < NT; ++j)
            #pragma unroll
            for (int k = 0; k < KS; ++k) {
                short8 bf_ = *(const short8*)&bl[(j * 16 + m) * P + k * 32 + q * 8];
                acc[j] = __builtin_amdgcn_mfma_f32_16x16x32_bf16(
                    pass ? af2[k] : af1[k], bf_, acc[j], 0, 0, 0);
            }
    }

    __syncthreads();
    #pragma unroll
    for (int j = 0; j < NT; ++j)
        #pragma unroll
        for (int r = 0; r < 4; ++r)
            accL[(wave * 16 + q * 4 + r) * CW + j * 16 + m] = acc[j][r];
    __syncthreads();

    // h2n = h2 + eps*tanh(acc + b_a2) -> aggT
    {
        const int c0 = lane * 2;
        if (c0 < 64) {
            float2 bv = {bias[c0], bias[c0 + 1]};
            #pragma unroll
            for (int rl = 0; rl < 16; ++rl) {
                int rowD = rowbase + rl;
                float n0 = 0.f, n1 = 0.f;
                if (rowD < NNODE) {
                    float2 v = *(const float2*)&accL[(wave * 16 + rl) * CW + c0];
                    long long o = (long long)rowD * 64 + c0;
                    ushort2 hh = *(const ushort2*)&hA[o];
                    n0 = bf2f(hh.x) + EPSC * ftanh(v.x + bv.x);
                    n1 = bf2f(hh.y) + EPSC * ftanh(v.y + bv.y);
                }
                ushort2 ob; ob.x = f2bf(n0); ob.y = f2bf(n1);
                *(ushort2*)&aggT[(wave * 16 + rl) * P + c0] = ob;
            }
        }
    }
    __syncthreads();

    short8 af4[KS];
    #pragma unroll
    for (int k = 0; k < KS; ++k)
        af4[k] = *(const short8*)&aggT[(wave * 16 + m) * P + k * 32 + q * 8];

    // stage wfc [40,64], zero-pad to 48 rows
    for (int t = threadIdx.x; t < 384; t += 256) {
        int r = t >> 3, c = t & 7;
        short8 v = z8;
        if (r < 40) v = *(const short8*)&wfcB[(long long)r * K + c * 8];
        *(short8*)&bl[r * P + c * 8] = v;
    }
    __syncthreads();

    f32x4 acc3[3];
    #pragma unroll
    for (int j = 0; j < 3; ++j) acc3[j] = (f32x4){0.f,0.f,0.f,0.f};
    #pragma unroll
    for (int j = 0; j < 3; ++j)
        #pragma unroll
        for (int k = 0; k < KS; ++k) {
            short8 bf_ = *(const short8*)&bl[(j * 16 + m) * P + k * 32 + q * 8];
            acc3[j] = __builtin_amdgcn_mfma_f32_16x16x32_bf16(af4[k], bf_, acc3[j], 0, 0, 0);
        }

    __syncthreads();
    constexpr int CW3 = 49;
    #pragma unroll
    for (int j = 0; j < 3; ++j)
        #pragma unroll
        for (int r = 0; r < 4; ++r)
            accL[(wave * 16 + q * 4 + r) * CW3 + j * 16 + m] = acc3[j][r];
    __syncthreads();

    float mrow = 0.f, lrow = 0.f;
    if (lane < 16) {
        const float* rp = &accL[(wave * 16 + lane) * CW3];
        float mx = -1e30f;
        for (int c = 0; c < 40; ++c) mx = fmaxf(mx, rp[c] + bfc[c]);
        float s = 0.f;
        for (int c = 0; c < 40; ++c) s += expf(rp[c] + bfc[c] - mx);
        mrow = mx; lrow = logf(s);
    }
    for (int rl = 0; rl < 16; ++rl) {
        float mm = __shfl(mrow, rl);
        float ll = __shfl(lrow, rl);
        int rowD = rowbase + rl;
        if (rowD < NNODE && lane < 40) {
            float v = accL[(wave * 16 + rl) * CW3 + lane] + bfc[lane];
            outF[(long long)rowD * 40 + lane] = v - mm - ll;
        }
    }
}

// ---- the persistent mega-kernel: 12 phases, 11 grid barriers, 1 launch ----
__global__ __launch_bounds__(256, 4) void mega(
    const float* __restrict__ x, const int* __restrict__ ei,
    const float* __restrict__ w_hid, const float* __restrict__ b_hid,
    const float* __restrict__ W_a1, const float* __restrict__ gcn1, const float* __restrict__ b_a1,
    const float* __restrict__ w2, const float* __restrict__ b2,
    const float* __restrict__ W_a2, const float* __restrict__ gcn2, const float* __restrict__ b_a2,
    const float* __restrict__ wfc, const float* __restrict__ bfc,
    float* __restrict__ ws, float* __restrict__ out)
{
    __shared__ __align__(16) char smem[34816];

    float* dinv   = ws + O_DINV;
    int*   degi   = (int*)(ws + O_DEGI);
    int*   rowptr = (int*)(ws + O_ROWPTR);
    int*   cursor = (int*)(ws + O_CURSOR);
    int*   gcur   = (int*)(ws + O_GCUR);
    int2*  ecsr   = (int2*)(ws + O_ECSR);
    u16* whB  = (u16*)(ws + O_WHB);
    u16* g1tB = (u16*)(ws + O_G1TB);
    u16* aw1B = (u16*)(ws + O_AW1B);
    u16* w2B  = (u16*)(ws + O_W2B);
    u16* aw2B = (u16*)(ws + O_AW2B);
    u16* g2tB = (u16*)(ws + O_G2TB);
    u16* wfcB = (u16*)(ws + O_WFCB);
    u16* aggB = (u16*)(ws + O_AGGB);
    u16* hB0  = (u16*)(ws + O_HB0);
    u16* hB1  = (u16*)(ws + O_HB1);
    u16* s0   = (u16*)(ws + O_S0);
    u16* s1   = (u16*)(ws + O_S1);

    // ---- A: weight prep + degi/gcur zero ----
    {
        constexpr int TOT = 84480 + NNODE + 1;
        for (int j0 = blockIdx.x * 256 + threadIdx.x; j0 < TOT; j0 += NBLK * 256) {
            int j = j0;
            if (j < 32768) { whB[j] = f2bf(w_hid[j]); continue; } j -= 32768;
            if (j < 16384) { int r=j>>7, c=j&127; g1tB[j] = f2bf(gcn1[c*128+r]); continue; } j -= 16384;
            if (j < 16384) { int r=j>>7, c=j&127;
                             aw1B[j] = f2bf(W_a1[r*128+c] - W_a1[c*128+r] - (r==c?GAMMAC:0.f));
                             continue; } j -= 16384;
            if (j < 8192)  { w2B[j] = f2bf(w2[j]); continue; } j -= 8192;
            if (j < 4096)  { int r=j>>6, c=j&63;
                             aw2B[j] = f2bf(W_a2[r*64+c] - W_a2[c*64+r] - (r==c?GAMMAC:0.f));
                             continue; } j -= 4096;
            if (j < 4096)  { int r=j>>6, c=j&63; g2tB[j] = f2bf(gcn2[c*64+r]); continue; } j -= 4096;
            if (j < 2560)  { wfcB[j] = f2bf(wfc[j]); continue; } j -= 2560;
            if (j < NNODE) { degi[j] = 0; continue; } j -= NNODE;
            if (j == 0)    { *gcur = 0; }
        }
    }
    gridsync();

    // ---- B: x@w_hid GEMM (blocks < NTILE)  ||  deg-count (blocks >= NTILE) ----
    if (blockIdx.x < NTILE) {
        ph_mgemm_x(smem, x, whB, b_hid, hB0, s0);
    } else {
        for (int e = (blockIdx.x - NTILE) * 256 + threadIdx.x; e < NEDGE; e += DEGB * 256)
            atomicAdd(&degi[ei[NEDGE + e]], 1);
    }
    gridsync();

    // ---- C: alloc (rowptr/cursor/dinv) ----
    for (int i = blockIdx.x * 256 + threadIdx.x; i < NNODE; i += NBLK * 256) {
        int d = degi[i];
        dinv[i] = rsqrtf(1.0f + (float)d);
        int pos = atomicAdd(gcur, d);
        rowptr[i] = pos;
        cursor[i] = pos;
    }
    gridsync();

    // ---- D: fill ecsr ----
    for (int e = blockIdx.x * 256 + threadIdx.x; e < NEDGE; e += NBLK * 256) {
        int s = ei[e], d = ei[NEDGE + e];
        int pos = atomicAdd(&cursor[d], 1);
        int2 v;
        v.x = s;
        v.y = __float_as_int(dinv[s] * dinv[d]);
        ecsr[pos] = v;
    }
    gridsync();

    // ---- conv1 iter 1 ----
    ph_gather<128>(rowptr, degi, ecsr, dinv, (const u32*)s0, aggB);
    gridsync();
    if (blockIdx.x < NTILE)
        ph_conv1<0>(smem, hB0, aggB, aw1B, g1tB, b_a1, hB1, s1, nullptr, nullptr);
    gridsync();

    // ---- conv1 iter 2 ----
    ph_gather<128>(rowptr, degi, ecsr, dinv, (const u32*)s1, aggB);
    gridsync();
    if (blockIdx.x < NTILE)
        ph_conv1<0>(smem, hB1, aggB, aw1B, g1tB, b_a1, hB0, s0, nullptr, nullptr);
    gridsync();

    // ---- conv1 iter 3 + fused h2 GEMM ----
    ph_gather<128>(rowptr, degi, ecsr, dinv, (const u32*)s0, aggB);
    gridsync();
    if (blockIdx.x < NTILE)
        ph_conv1<1>(smem, hB0, aggB, aw1B, g1tB, b_a1, hB1, s1, w2B, b2);
    gridsync();

    // ---- conv2 + FC + log_softmax ----
    ph_gather<64>(rowptr, degi, ecsr, dinv, (const u32*)s1, aggB);
    gridsync();
    if (blockIdx.x < NTILE)
        ph_conv2fc(smem, hB1, aggB, aw2B, g2tB, b_a2, wfcB, bfc, out);
}

extern "C" void kernel_launch(void* const* d_in, const int* in_sizes, int n_in,
                              void* d_out, int out_size, void* d_ws, size_t ws_size,
                              hipStream_t stream) {
    const float* x     = (const float*)d_in[0];
    const int*   ei    = (const int*)d_in[1];
    const float* w_hid = (const float*)d_in[2];
    const float* b_hid = (const float*)d_in[3];
    const float* W_a1  = (const float*)d_in[4];
    const float* gcn1  = (const float*)d_in[5];
    const float* b_a1  = (const float*)d_in[6];
    const float* w2    = (const float*)d_in[7];
    const float* b2    = (const float*)d_in[8];
    const float* W_a2  = (const float*)d_in[9];
    const float* gcn2  = (const float*)d_in[10];
    const float* b_a2  = (const float*)d_in[11];
    const float* wfc   = (const float*)d_in[12];
    const float* bfc   = (const float*)d_in[13];

    mega<<<NBLK, 256, 0, stream>>>(
        x, ei, w_hid, b_hid, W_a1, gcn1, b_a1, w2, b2, W_a2, gcn2, b_a2,
        wfc, bfc, (float*)d_ws, (float*)d_out);
}

// Round 4
// 1692.755 us; speedup vs baseline: 2.2879x; 2.2879x over previous
//
#include <hip/hip_runtime.h>
#include <hip/hip_bf16.h>
#include <math.h>

typedef unsigned short u16;
typedef unsigned int   u32;
using short8  = __attribute__((ext_vector_type(8))) short;
using f32x4   = __attribute__((ext_vector_type(4))) float;

static constexpr int NNODE = 50000;
static constexpr int NEDGE = 600000;
static constexpr float EPSC   = 0.1f;
static constexpr float GAMMAC = 0.1f;

static constexpr int NBLK  = 1024;                 // 256 CU x 4 blocks/CU (co-resident)
static constexpr int NTILE = (NNODE + 63) / 64;    // 782 GEMM row-tiles
static constexpr int DEGB  = NBLK - NTILE;         // 242 deg-count blocks in phase B

// ---- workspace layout (float-index offsets) ----
static constexpr long long O_DINV   = 0;                         // float 50000
static constexpr long long O_DEGI   = 50000;                     // int 50000
static constexpr long long O_ROWPTR = 100000;                    // int 50000
static constexpr long long O_CURSOR = 150004;                    // int 50000
static constexpr long long O_GCUR   = 200052;                    // int 1
static constexpr long long O_ECSR   = 200260;                    // int2 600000
// bf16 weights
static constexpr long long O_WHB    = 1400260;                   // 32768 bf16
static constexpr long long O_G1TB   = O_WHB  + 16384;
static constexpr long long O_AW1B   = O_G1TB + 8192;
static constexpr long long O_W2B    = O_AW1B + 8192;
static constexpr long long O_AW2B   = O_W2B  + 4096;
static constexpr long long O_G2TB   = O_AW2B + 2048;
static constexpr long long O_WFCB   = O_G2TB + 2048;
// big buffers
static constexpr long long O_AGGB   = 3450004;                   // bf16 6.4M
static constexpr long long O_HB0    = O_AGGB + 3200000;          // bf16 6.4M
static constexpr long long O_HB1    = O_HB0  + 3200000;          // bf16 6.4M
static constexpr long long O_S0     = O_HB1  + 3200000;          // fp8 6.4M
static constexpr long long O_S1     = O_S0   + 1600000;          // fp8 6.4M

__device__ __forceinline__ float bf2f(u16 u) {
    return __uint_as_float(((unsigned)u) << 16);
}
__device__ __forceinline__ u16 f2bf(float f) {
    unsigned u = __float_as_uint(f);
    return (u16)((u + 0x7FFFu + ((u >> 16) & 1u)) >> 16);
}
__device__ __forceinline__ float ftanh(float x) {
    float x2 = fminf(fmaxf(2.f * x, -30.f), 30.f);
    float e = __expf(x2);
    return (e - 1.f) * __builtin_amdgcn_rcpf(e + 1.f);
}
__device__ __forceinline__ u16 pk_fp8(float a, float b) {
    int pk = __builtin_amdgcn_cvt_pk_fp8_f32(a, b, 0, false);
    return (u16)(pk & 0xffff);
}
__device__ __forceinline__ void acc_fp8x4(float* a, u32 v, float w) {
    a[0] += __builtin_amdgcn_cvt_f32_fp8(v, 0) * w;
    a[1] += __builtin_amdgcn_cvt_f32_fp8(v, 1) * w;
    a[2] += __builtin_amdgcn_cvt_f32_fp8(v, 2) * w;
    a[3] += __builtin_amdgcn_cvt_f32_fp8(v, 3) * w;
}

// ---- device-scope grid barrier, coherence-storm-free ----
// Round-3 lesson: per-thread __threadfence (buffer_wbl2/inv sc1 = FULL L2 cache-ops)
// and ACQUIRE polling (buffer_inv per poll!) invalidated the L2 under still-running
// blocks -> 330us/barrier. Fix: thread0-only fences (1 wbl2+inv pair per block per
// barrier) and RELAXED polls (agent-scope atomics read the coherence point; no inv).
__device__ int g_bar = 0;
__device__ int g_gen = 0;

__device__ __forceinline__ void gridsync() {
    __syncthreads();                   // all waves' prior mem ops complete (waitcnt)
    if (threadIdx.x == 0) {
        __threadfence();               // release: one L2 writeback for this block
        int g = __hip_atomic_load(&g_gen, __ATOMIC_RELAXED, __HIP_MEMORY_SCOPE_AGENT);
        if (__hip_atomic_fetch_add(&g_bar, 1, __ATOMIC_RELAXED, __HIP_MEMORY_SCOPE_AGENT)
            == (int)gridDim.x - 1) {
            __hip_atomic_store(&g_bar, 0, __ATOMIC_RELAXED, __HIP_MEMORY_SCOPE_AGENT);
            __hip_atomic_store(&g_gen, g + 1, __ATOMIC_RELEASE, __HIP_MEMORY_SCOPE_AGENT);
        } else {
            while (__hip_atomic_load(&g_gen, __ATOMIC_RELAXED, __HIP_MEMORY_SCOPE_AGENT) == g)
                __builtin_amdgcn_s_sleep(16);
        }
        __threadfence();               // acquire: one L1/L2 invalidate for this block
    }
    __syncthreads();
}

// ---- phase: x @ w_hid^T -> leaky -> hB0 + fp8 shadow (one 64-row tile/block) ----
__device__ __forceinline__ void ph_mgemm_x(char* smem, const float* __restrict__ x,
        const u16* __restrict__ Bt, const float* __restrict__ bias,
        u16* __restrict__ outB, u16* __restrict__ outB8) {
    constexpr int K = 256, KCHU = 128, KC = 4, P = 136, CW = 129;
    u16*   bl   = (u16*)smem;
    float* accL = (float*)smem;
    const int wave = threadIdx.x >> 6, lane = threadIdx.x & 63;
    const int m = lane & 15, q = lane >> 4;
    const int rowbase = blockIdx.x * 64 + wave * 16;
    const int row = rowbase + m;
    const bool rok = row < NNODE;
    const short8 z8 = {0,0,0,0,0,0,0,0};

    short8 af[8];
    {
        const float* apf = x + (long long)row * K;
        #pragma unroll
        for (int k = 0; k < 8; ++k) {
            short8 t = z8;
            if (rok) {
                const float4* p = (const float4*)(apf + (k * 4 + q) * 8);
                float4 a = p[0], b = p[1];
                t[0]=(short)f2bf(a.x); t[1]=(short)f2bf(a.y); t[2]=(short)f2bf(a.z); t[3]=(short)f2bf(a.w);
                t[4]=(short)f2bf(b.x); t[5]=(short)f2bf(b.y); t[6]=(short)f2bf(b.z); t[7]=(short)f2bf(b.w);
            }
            af[k] = t;
        }
    }

    f32x4 acc[8];
    #pragma unroll
    for (int j = 0; j < 8; ++j) acc[j] = (f32x4){0.f,0.f,0.f,0.f};

    for (int ch = 0; ch < 2; ++ch) {
        if (ch) __syncthreads();
        for (int t = threadIdx.x; t < 2048; t += 256) {
            int r = t >> 4, c = t & 15;
            *(short8*)&bl[r * P + c * 8] = *(const short8*)&Bt[(long long)r * K + ch * KCHU + c * 8];
        }
        __syncthreads();
        #pragma unroll
        for (int j = 0; j < 8; ++j)
            #pragma unroll
            for (int k = 0; k < KC; ++k) {
                short8 bf_ = *(const short8*)&bl[(j * 16 + m) * P + k * 32 + q * 8];
                acc[j] = __builtin_amdgcn_mfma_f32_16x16x32_bf16(af[ch * KC + k], bf_, acc[j], 0, 0, 0);
            }
    }

    __syncthreads();
    #pragma unroll
    for (int j = 0; j < 8; ++j)
        #pragma unroll
        for (int r = 0; r < 4; ++r)
            accL[(wave * 16 + q * 4 + r) * CW + j * 16 + m] = acc[j][r];
    __syncthreads();

    const int c0 = lane * 2;
    float2 bv = {bias[c0], bias[c0 + 1]};
    #pragma unroll
    for (int rl = 0; rl < 16; ++rl) {
        int rowD = rowbase + rl;
        if (rowD >= NNODE) continue;
        float2 v = *(const float2*)&accL[(wave * 16 + rl) * CW + c0];
        v.x += bv.x; v.y += bv.y;
        v.x = v.x > 0.f ? v.x : 0.01f * v.x;
        v.y = v.y > 0.f ? v.y : 0.01f * v.y;
        long long o = (long long)rowD * 128 + c0;
        ushort2 ob; ob.x = f2bf(v.x); ob.y = f2bf(v.y);
        *(ushort2*)&outB[o] = ob;
        outB8[o >> 1] = pk_fp8(v.x, v.y);
    }
}

// ---- phase: CSR gather (fp8 in, bf16 out), grid-strided wave-per-node ----
template<int HD>
__device__ __forceinline__ void ph_gather(const int* __restrict__ rowptr,
        const int* __restrict__ degi, const int2* __restrict__ ecsr,
        const float* __restrict__ dinv, const u32* __restrict__ g8,
        u16* __restrict__ aggB) {
    const int lane = threadIdx.x & 63;
    const int qr = lane >> 4, l4 = lane & 15;
    constexpr int EL = (HD == 128) ? 8 : 4;
    for (int node = blockIdx.x * 4 + (threadIdx.x >> 6); node < NNODE; node += NBLK * 4) {
        const int r0 = rowptr[node];
        const int r1 = r0 + degi[node];
        const float wself = dinv[node] * dinv[node];
        float a[EL];
        #pragma unroll
        for (int i = 0; i < EL; ++i) a[i] = 0.f;
        if (qr == 0) {
            if (HD == 128) {
                uint2 gv = ((const uint2*)g8)[(long long)node * 16 + l4];
                acc_fp8x4(a, gv.x, wself);
                acc_fp8x4(a + 4, gv.y, wself);
            } else {
                u32 gv = g8[(long long)node * 16 + l4];
                acc_fp8x4(a, gv, wself);
            }
        }
        for (int base = r0; base < r1; base += 64) {
            int idx = base + lane;
            int cs = 0; float cw = 0.f;
            if (idx < r1) { int2 ev = ecsr[idx]; cs = ev.x; cw = __int_as_float(ev.y); }
            int cnt = min(64, r1 - base);
            // 4 rounds (16 edges) per step: padded with zero-weight lanes -> 4 loads in flight
            for (int j = 0; j < cnt; j += 16) {
                #pragma unroll
                for (int u = 0; u < 4; ++u) {
                    int jj = j + u * 4 + qr;
                    int   s = __shfl(cs, jj);
                    float w = __shfl(cw, jj);
                    if (HD == 128) {
                        uint2 gv = ((const uint2*)g8)[(long long)s * 16 + l4];
                        acc_fp8x4(a, gv.x, w);
                        acc_fp8x4(a + 4, gv.y, w);
                    } else {
                        u32 gv = g8[(long long)s * 16 + l4];
                        acc_fp8x4(a, gv, w);
                    }
                }
            }
        }
        #pragma unroll
        for (int i = 0; i < EL; ++i) {
            a[i] += __shfl_xor(a[i], 16);
            a[i] += __shfl_xor(a[i], 32);
        }
        if (HD == 128) {
            float v0 = (qr == 0) ? a[0] : (qr == 1) ? a[2] : (qr == 2) ? a[4] : a[6];
            float v1 = (qr == 0) ? a[1] : (qr == 1) ? a[3] : (qr == 2) ? a[5] : a[7];
            long long o = (long long)node * 128 + l4 * 8 + qr * 2;
            ushort2 ob; ob.x = f2bf(v0); ob.y = f2bf(v1);
            *(ushort2*)&aggB[o] = ob;
        } else {
            float v = (qr == 0) ? a[0] : (qr == 1) ? a[1] : (qr == 2) ? a[2] : a[3];
            aggB[(long long)node * 64 + l4 * 4 + qr] = f2bf(v);
        }
    }
}

// ---- phase: conv1 step GEMM (+optional fused h2 GEMM), one 64-row tile/block ----
template<int TAIL>
__device__ __forceinline__ void ph_conv1(char* smem, const u16* __restrict__ hA,
        const u16* __restrict__ gA, const u16* __restrict__ BtW, const u16* __restrict__ BtG,
        const float* __restrict__ bias, u16* __restrict__ outB, u16* __restrict__ outB8,
        const u16* __restrict__ w2W, const float* __restrict__ b2) {
    constexpr int K = 128, KS = 4, P = 136, CW = 129;
    u16*   bl   = (u16*)smem;
    float* accL = (float*)smem;
    const int wave = threadIdx.x >> 6, lane = threadIdx.x & 63;
    const int m = lane & 15, q = lane >> 4;
    const int rowbase = blockIdx.x * 64 + wave * 16;
    const int row = rowbase + m;
    const bool rok = row < NNODE;
    const short8 z8 = {0,0,0,0,0,0,0,0};

    short8 af1[KS], af2[KS];
    {
        const short8* ap1 = (const short8*)(hA + (long long)row * K);
        const short8* ap2 = (const short8*)(gA + (long long)row * K);
        #pragma unroll
        for (int k = 0; k < KS; ++k) {
            af1[k] = rok ? ap1[k * 4 + q] : z8;
            af2[k] = rok ? ap2[k * 4 + q] : z8;
        }
    }

    f32x4 acc[8];
    #pragma unroll
    for (int j = 0; j < 8; ++j) acc[j] = (f32x4){0.f,0.f,0.f,0.f};

    #pragma unroll
    for (int pass = 0; pass < 2; ++pass) {
        const u16* Bcur = pass ? BtG : BtW;
        if (pass) __syncthreads();
        for (int t = threadIdx.x; t < 2048; t += 256) {
            int r = t >> 4, c = t & 15;
            *(short8*)&bl[r * P + c * 8] = *(const short8*)&Bcur[(long long)r * K + c * 8];
        }
        __syncthreads();
        #pragma unroll
        for (int j = 0; j < 8; ++j)
            #pragma unroll
            for (int k = 0; k < KS; ++k) {
                short8 bf_ = *(const short8*)&bl[(j * 16 + m) * P + k * 32 + q * 8];
                acc[j] = __builtin_amdgcn_mfma_f32_16x16x32_bf16(
                    pass ? af2[k] : af1[k], bf_, acc[j], 0, 0, 0);
            }
    }

    __syncthreads();
    #pragma unroll
    for (int j = 0; j < 8; ++j)
        #pragma unroll
        for (int r = 0; r < 4; ++r)
            accL[(wave * 16 + q * 4 + r) * CW + j * 16 + m] = acc[j][r];
    __syncthreads();

    const int c0 = lane * 2;
    if (TAIL == 0) {
        float2 bv = {bias[c0], bias[c0 + 1]};
        #pragma unroll
        for (int rl = 0; rl < 16; ++rl) {
            int rowD = rowbase + rl;
            if (rowD >= NNODE) continue;
            float2 v = *(const float2*)&accL[(wave * 16 + rl) * CW + c0];
            long long o = (long long)rowD * K + c0;
            ushort2 hh = *(const ushort2*)&hA[o];
            float n0 = bf2f(hh.x) + EPSC * ftanh(v.x + bv.x);
            float n1 = bf2f(hh.y) + EPSC * ftanh(v.y + bv.y);
            ushort2 ob; ob.x = f2bf(n0); ob.y = f2bf(n1);
            *(ushort2*)&outB[o] = ob;
            outB8[o >> 1] = pk_fp8(n0, n1);
        }
        return;
    }

    // TAIL: leaky(h_new) into regs, then LDS tile [0,17408) + w2 [17408,34816)
    u32 hv[16];
    {
        float2 bv = {bias[c0], bias[c0 + 1]};
        #pragma unroll
        for (int rl = 0; rl < 16; ++rl) {
            int rowD = rowbase + rl;
            float n0 = 0.f, n1 = 0.f;
            if (rowD < NNODE) {
                float2 v = *(const float2*)&accL[(wave * 16 + rl) * CW + c0];
                long long o = (long long)rowD * K + c0;
                ushort2 hh = *(const ushort2*)&hA[o];
                n0 = bf2f(hh.x) + EPSC * ftanh(v.x + bv.x);
                n1 = bf2f(hh.y) + EPSC * ftanh(v.y + bv.y);
                n0 = n0 > 0.f ? n0 : 0.01f * n0;
                n1 = n1 > 0.f ? n1 : 0.01f * n1;
            }
            hv[rl] = (u32)f2bf(n0) | ((u32)f2bf(n1) << 16);
        }
    }
    __syncthreads();   // everyone done reading accL; smem repurposed

    u16* aggT = (u16*)smem;            // [64][136] bf16, 17408 B
    u16* bl2  = (u16*)(smem + 17408);  // w2 [64][136] bf16, 17408 B
    #pragma unroll
    for (int rl = 0; rl < 16; ++rl)
        *(u32*)&aggT[(wave * 16 + rl) * P + c0] = hv[rl];
    for (int t = threadIdx.x; t < 1024; t += 256) {
        int r = t >> 4, c = t & 15;
        *(short8*)&bl2[r * P + c * 8] = *(const short8*)&w2W[(long long)r * K + c * 8];
    }
    __syncthreads();

    short8 af3[4];
    #pragma unroll
    for (int k = 0; k < 4; ++k)
        af3[k] = *(const short8*)&aggT[(wave * 16 + m) * P + k * 32 + q * 8];

    f32x4 acc2[4];
    #pragma unroll
    for (int j = 0; j < 4; ++j) acc2[j] = (f32x4){0.f,0.f,0.f,0.f};
    #pragma unroll
    for (int j = 0; j < 4; ++j)
        #pragma unroll
        for (int k = 0; k < 4; ++k) {
            short8 bf_ = *(const short8*)&bl2[(j * 16 + m) * P + k * 32 + q * 8];
            acc2[j] = __builtin_amdgcn_mfma_f32_16x16x32_bf16(af3[k], bf_, acc2[j], 0, 0, 0);
        }

    __syncthreads();
    constexpr int CW2 = 65;
    float* accL2 = (float*)smem;       // 16640 B, overwrites aggT (af3 already in regs)
    #pragma unroll
    for (int j = 0; j < 4; ++j)
        #pragma unroll
        for (int r = 0; r < 4; ++r)
            accL2[(wave * 16 + q * 4 + r) * CW2 + j * 16 + m] = acc2[j][r];
    __syncthreads();

    if (c0 < 64) {
        float2 bv = {b2[c0], b2[c0 + 1]};
        #pragma unroll
        for (int rl = 0; rl < 16; ++rl) {
            int rowD = rowbase + rl;
            if (rowD >= NNODE) continue;
            float2 v = *(const float2*)&accL2[(wave * 16 + rl) * CW2 + c0];
            v.x += bv.x; v.y += bv.y;
            v.x = v.x > 0.f ? v.x : 0.01f * v.x;
            v.y = v.y > 0.f ? v.y : 0.01f * v.y;
            long long o = (long long)rowD * 64 + c0;
            ushort2 ob; ob.x = f2bf(v.x); ob.y = f2bf(v.y);
            *(ushort2*)&outB[o] = ob;
            outB8[o >> 1] = pk_fp8(v.x, v.y);
        }
    }
}

// ---- phase: conv2 + FC + log_softmax, one 64-row tile/block ----
__device__ __forceinline__ void ph_conv2fc(char* smem, const u16* __restrict__ hA,
        const u16* __restrict__ gA, const u16* __restrict__ BtW, const u16* __restrict__ BtG,
        const float* __restrict__ bias, const u16* __restrict__ wfcB,
        const float* __restrict__ bfc, float* __restrict__ outF) {
    constexpr int K = 64, NT = 4, KS = 2, P = 72, CW = 65;
    constexpr int R1 = 64 * CW * 4;    // 16640
    u16*   bl   = (u16*)smem;
    float* accL = (float*)smem;
    u16*   aggT = (u16*)(smem + R1);   // [64][72] bf16, 9216 B
    const int wave = threadIdx.x >> 6, lane = threadIdx.x & 63;
    const int m = lane & 15, q = lane >> 4;
    const int rowbase = blockIdx.x * 64 + wave * 16;
    const int row = rowbase + m;
    const bool rok = row < NNODE;
    const short8 z8 = {0,0,0,0,0,0,0,0};

    short8 af1[KS], af2[KS];
    {
        const short8* ap1 = (const short8*)(hA + (long long)row * K);
        const short8* ap2 = (const short8*)(gA + (long long)row * K);
        #pragma unroll
        for (int k = 0; k < KS; ++k) {
            af1[k] = rok ? ap1[k * 4 + q] : z8;
            af2[k] = rok ? ap2[k * 4 + q] : z8;
        }
    }

    f32x4 acc[NT];
    #pragma unroll
    for (int j = 0; j < NT; ++j) acc[j] = (f32x4){0.f,0.f,0.f,0.f};

    #pragma unroll
    for (int pass = 0; pass < 2; ++pass) {
        const u16* Bcur = pass ? BtG : BtW;
        if (pass) __syncthreads();
        for (int t = threadIdx.x; t < 512; t += 256) {
            int r = t >> 3, c = t & 7;
            *(short8*)&bl[r * P + c * 8] = *(const short8*)&Bcur[(long long)r * K + c * 8];
        }
        __syncthreads();
        #pragma unroll
        for (int j = 0; j < NT; ++j)
            #pragma unroll
            for (int k = 0; k < KS; ++k) {
                short8 bf_ = *(const short8*)&bl[(j * 16 + m) * P + k * 32 + q * 8];
                acc[j] = __builtin_amdgcn_mfma_f32_16x16x32_bf16(
                    pass ? af2[k] : af1[k], bf_, acc[j], 0, 0, 0);
            }
    }

    __syncthreads();
    #pragma unroll
    for (int j = 0; j < NT; ++j)
        #pragma unroll
        for (int r = 0; r < 4; ++r)
            accL[(wave * 16 + q * 4 + r) * CW + j * 16 + m] = acc[j][r];
    __syncthreads();

    // h2n = h2 + eps*tanh(acc + b_a2) -> aggT
    {
        const int c0 = lane * 2;
        if (c0 < 64) {
            float2 bv = {bias[c0], bias[c0 + 1]};
            #pragma unroll
            for (int rl = 0; rl < 16; ++rl) {
                int rowD = rowbase + rl;
                float n0 = 0.f, n1 = 0.f;
                if (rowD < NNODE) {
                    float2 v = *(const float2*)&accL[(wave * 16 + rl) * CW + c0];
                    long long o = (long long)rowD * 64 + c0;
                    ushort2 hh = *(const ushort2*)&hA[o];
                    n0 = bf2f(hh.x) + EPSC * ftanh(v.x + bv.x);
                    n1 = bf2f(hh.y) + EPSC * ftanh(v.y + bv.y);
                }
                ushort2 ob; ob.x = f2bf(n0); ob.y = f2bf(n1);
                *(ushort2*)&aggT[(wave * 16 + rl) * P + c0] = ob;
            }
        }
    }
    __syncthreads();

    short8 af4[KS];
    #pragma unroll
    for (int k = 0; k < KS; ++k)
        af4[k] = *(const short8*)&aggT[(wave * 16 + m) * P + k * 32 + q * 8];

    // stage wfc [40,64], zero-pad to 48 rows
    for (int t = threadIdx.x; t < 384; t += 256) {
        int r = t >> 3, c = t & 7;
        short8 v = z8;
        if (r < 40) v = *(const short8*)&wfcB[(long long)r * K + c * 8];
        *(short8*)&bl[r * P + c * 8] = v;
    }
    __syncthreads();

    f32x4 acc3[3];
    #pragma unroll
    for (int j = 0; j < 3; ++j) acc3[j] = (f32x4){0.f,0.f,0.f,0.f};
    #pragma unroll
    for (int j = 0; j < 3; ++j)
        #pragma unroll
        for (int k = 0; k < KS; ++k) {
            short8 bf_ = *(const short8*)&bl[(j * 16 + m) * P + k * 32 + q * 8];
            acc3[j] = __builtin_amdgcn_mfma_f32_16x16x32_bf16(af4[k], bf_, acc3[j], 0, 0, 0);
        }

    __syncthreads();
    constexpr int CW3 = 49;
    #pragma unroll
    for (int j = 0; j < 3; ++j)
        #pragma unroll
        for (int r = 0; r < 4; ++r)
            accL[(wave * 16 + q * 4 + r) * CW3 + j * 16 + m] = acc3[j][r];
    __syncthreads();

    float mrow = 0.f, lrow = 0.f;
    if (lane < 16) {
        const float* rp = &accL[(wave * 16 + lane) * CW3];
        float mx = -1e30f;
        for (int c = 0; c < 40; ++c) mx = fmaxf(mx, rp[c] + bfc[c]);
        float s = 0.f;
        for (int c = 0; c < 40; ++c) s += expf(rp[c] + bfc[c] - mx);
        mrow = mx; lrow = logf(s);
    }
    for (int rl = 0; rl < 16; ++rl) {
        float mm = __shfl(mrow, rl);
        float ll = __shfl(lrow, rl);
        int rowD = rowbase + rl;
        if (rowD < NNODE && lane < 40) {
            float v = accL[(wave * 16 + rl) * CW3 + lane] + bfc[lane];
            outF[(long long)rowD * 40 + lane] = v - mm - ll;
        }
    }
}

// ---- the persistent mega-kernel: 12 phases, 11 grid barriers, 1 launch ----
__global__ __launch_bounds__(256, 4) void mega(
    const float* __restrict__ x, const int* __restrict__ ei,
    const float* __restrict__ w_hid, const float* __restrict__ b_hid,
    const float* __restrict__ W_a1, const float* __restrict__ gcn1, const float* __restrict__ b_a1,
    const float* __restrict__ w2, const float* __restrict__ b2,
    const float* __restrict__ W_a2, const float* __restrict__ gcn2, const float* __restrict__ b_a2,
    const float* __restrict__ wfc, const float* __restrict__ bfc,
    float* __restrict__ ws, float* __restrict__ out)
{
    __shared__ __align__(16) char smem[34816];

    float* dinv   = ws + O_DINV;
    int*   degi   = (int*)(ws + O_DEGI);
    int*   rowptr = (int*)(ws + O_ROWPTR);
    int*   cursor = (int*)(ws + O_CURSOR);
    int*   gcur   = (int*)(ws + O_GCUR);
    int2*  ecsr   = (int2*)(ws + O_ECSR);
    u16* whB  = (u16*)(ws + O_WHB);
    u16* g1tB = (u16*)(ws + O_G1TB);
    u16* aw1B = (u16*)(ws + O_AW1B);
    u16* w2B  = (u16*)(ws + O_W2B);
    u16* aw2B = (u16*)(ws + O_AW2B);
    u16* g2tB = (u16*)(ws + O_G2TB);
    u16* wfcB = (u16*)(ws + O_WFCB);
    u16* aggB = (u16*)(ws + O_AGGB);
    u16* hB0  = (u16*)(ws + O_HB0);
    u16* hB1  = (u16*)(ws + O_HB1);
    u16* s0   = (u16*)(ws + O_S0);
    u16* s1   = (u16*)(ws + O_S1);

    // ---- A: weight prep + degi/gcur zero ----
    {
        constexpr int TOT = 84480 + NNODE + 1;
        for (int j0 = blockIdx.x * 256 + threadIdx.x; j0 < TOT; j0 += NBLK * 256) {
            int j = j0;
            if (j < 32768) { whB[j] = f2bf(w_hid[j]); continue; } j -= 32768;
            if (j < 16384) { int r=j>>7, c=j&127; g1tB[j] = f2bf(gcn1[c*128+r]); continue; } j -= 16384;
            if (j < 16384) { int r=j>>7, c=j&127;
                             aw1B[j] = f2bf(W_a1[r*128+c] - W_a1[c*128+r] - (r==c?GAMMAC:0.f));
                             continue; } j -= 16384;
            if (j < 8192)  { w2B[j] = f2bf(w2[j]); continue; } j -= 8192;
            if (j < 4096)  { int r=j>>6, c=j&63;
                             aw2B[j] = f2bf(W_a2[r*64+c] - W_a2[c*64+r] - (r==c?GAMMAC:0.f));
                             continue; } j -= 4096;
            if (j < 4096)  { int r=j>>6, c=j&63; g2tB[j] = f2bf(gcn2[c*64+r]); continue; } j -= 4096;
            if (j < 2560)  { wfcB[j] = f2bf(wfc[j]); continue; } j -= 2560;
            if (j < NNODE) { degi[j] = 0; continue; } j -= NNODE;
            if (j == 0)    { *gcur = 0; }
        }
    }
    gridsync();

    // ---- B: x@w_hid GEMM (blocks < NTILE)  ||  deg-count (blocks >= NTILE) ----
    if (blockIdx.x < NTILE) {
        ph_mgemm_x(smem, x, whB, b_hid, hB0, s0);
    } else {
        for (int e = (blockIdx.x - NTILE) * 256 + threadIdx.x; e < NEDGE; e += DEGB * 256)
            atomicAdd(&degi[ei[NEDGE + e]], 1);
    }
    gridsync();

    // ---- C: alloc (rowptr/cursor/dinv) ----
    for (int i = blockIdx.x * 256 + threadIdx.x; i < NNODE; i += NBLK * 256) {
        int d = degi[i];
        dinv[i] = rsqrtf(1.0f + (float)d);
        int pos = atomicAdd(gcur, d);
        rowptr[i] = pos;
        cursor[i] = pos;
    }
    gridsync();

    // ---- D: fill ecsr ----
    for (int e = blockIdx.x * 256 + threadIdx.x; e < NEDGE; e += NBLK * 256) {
        int s = ei[e], d = ei[NEDGE + e];
        int pos = atomicAdd(&cursor[d], 1);
        int2 v;
        v.x = s;
        v.y = __float_as_int(dinv[s] * dinv[d]);
        ecsr[pos] = v;
    }
    gridsync();

    // ---- conv1 iter 1 ----
    ph_gather<128>(rowptr, degi, ecsr, dinv, (const u32*)s0, aggB);
    gridsync();
    if (blockIdx.x < NTILE)
        ph_conv1<0>(smem, hB0, aggB, aw1B, g1tB, b_a1, hB1, s1, nullptr, nullptr);
    gridsync();

    // ---- conv1 iter 2 ----
    ph_gather<128>(rowptr, degi, ecsr, dinv, (const u32*)s1, aggB);
    gridsync();
    if (blockIdx.x < NTILE)
        ph_conv1<0>(smem, hB1, aggB, aw1B, g1tB, b_a1, hB0, s0, nullptr, nullptr);
    gridsync();

    // ---- conv1 iter 3 + fused h2 GEMM ----
    ph_gather<128>(rowptr, degi, ecsr, dinv, (const u32*)s0, aggB);
    gridsync();
    if (blockIdx.x < NTILE)
        ph_conv1<1>(smem, hB0, aggB, aw1B, g1tB, b_a1, hB1, s1, w2B, b2);
    gridsync();

    // ---- conv2 + FC + log_softmax ----
    ph_gather<64>(rowptr, degi, ecsr, dinv, (const u32*)s1, aggB);
    gridsync();
    if (blockIdx.x < NTILE)
        ph_conv2fc(smem, hB1, aggB, aw2B, g2tB, b_a2, wfcB, bfc, out);
}

extern "C" void kernel_launch(void* const* d_in, const int* in_sizes, int n_in,
                              void* d_out, int out_size, void* d_ws, size_t ws_size,
                              hipStream_t stream) {
    const float* x     = (const float*)d_in[0];
    const int*   ei    = (const int*)d_in[1];
    const float* w_hid = (const float*)d_in[2];
    const float* b_hid = (const float*)d_in[3];
    const float* W_a1  = (const float*)d_in[4];
    const float* gcn1  = (const float*)d_in[5];
    const float* b_a1  = (const float*)d_in[6];
    const float* w2    = (const float*)d_in[7];
    const float* b2    = (const float*)d_in[8];
    const float* W_a2  = (const float*)d_in[9];
    const float* gcn2  = (const float*)d_in[10];
    const float* b_a2  = (const float*)d_in[11];
    const float* wfc   = (const float*)d_in[12];
    const float* bfc   = (const float*)d_in[13];

    mega<<<NBLK, 256, 0, stream>>>(
        x, ei, w_hid, b_hid, W_a1, gcn1, b_a1, w2, b2, W_a2, gcn2, b_a2,
        wfc, bfc, (float*)d_ws, (float*)d_out);
}

// Round 5
// 362.775 us; speedup vs baseline: 10.6756x; 4.6661x over previous
//
#include <hip/hip_runtime.h>
#include <hip/hip_bf16.h>
#include <math.h>

typedef unsigned short u16;
typedef unsigned int   u32;
using short8  = __attribute__((ext_vector_type(8))) short;
using f32x4   = __attribute__((ext_vector_type(4))) float;

static constexpr int NNODE = 50000;
static constexpr int NEDGE = 600000;
static constexpr float EPSC   = 0.1f;
static constexpr float GAMMAC = 0.1f;

static constexpr int NTILE = (NNODE + 63) / 64;    // 782 GEMM row-tiles
static constexpr int XDEG  = 242;                  // extra deg-count blocks in x-GEMM

// ---- workspace layout (float-index offsets) ----
static constexpr long long O_DINV   = 0;                         // float 50000
static constexpr long long O_DEGI   = 50000;                     // int 50000
static constexpr long long O_ROWPTR = 100000;                    // int 50000
static constexpr long long O_CURSOR = 150004;                    // int 50000
static constexpr long long O_GCUR   = 200052;                    // int 1
static constexpr long long O_ECSR   = 200260;                    // int2 600000
// bf16 weights
static constexpr long long O_WHB    = 1400260;                   // 32768 bf16
static constexpr long long O_G1TB   = O_WHB  + 16384;
static constexpr long long O_AW1B   = O_G1TB + 8192;
static constexpr long long O_W2B    = O_AW1B + 8192;
static constexpr long long O_AW2B   = O_W2B  + 4096;
static constexpr long long O_G2TB   = O_AW2B + 2048;
static constexpr long long O_WFCB   = O_G2TB + 2048;
// big buffers
static constexpr long long O_AGGB   = 3450004;                   // bf16 6.4M
static constexpr long long O_HB0    = O_AGGB + 3200000;          // bf16 6.4M
static constexpr long long O_HB1    = O_HB0  + 3200000;          // bf16 6.4M
static constexpr long long O_S0     = O_HB1  + 3200000;          // fp8 6.4M
static constexpr long long O_S1     = O_S0   + 1600000;          // fp8 6.4M

__device__ __forceinline__ float bf2f(u16 u) {
    return __uint_as_float(((unsigned)u) << 16);
}
__device__ __forceinline__ u16 f2bf(float f) {
    unsigned u = __float_as_uint(f);
    return (u16)((u + 0x7FFFu + ((u >> 16) & 1u)) >> 16);
}
// fast tanh: (e^{2x}-1)/(e^{2x}+1), clamped
__device__ __forceinline__ float ftanh(float x) {
    float x2 = fminf(fmaxf(2.f * x, -30.f), 30.f);
    float e = __expf(x2);
    return (e - 1.f) * __builtin_amdgcn_rcpf(e + 1.f);
}
// fp8 e4m3 pack/decode
__device__ __forceinline__ u16 pk_fp8(float a, float b) {
    int pk = __builtin_amdgcn_cvt_pk_fp8_f32(a, b, 0, false);
    return (u16)(pk & 0xffff);
}
__device__ __forceinline__ void acc_fp8x4(float* a, u32 v, float w) {
    a[0] += __builtin_amdgcn_cvt_f32_fp8(v, 0) * w;
    a[1] += __builtin_amdgcn_cvt_f32_fp8(v, 1) * w;
    a[2] += __builtin_amdgcn_cvt_f32_fp8(v, 2) * w;
    a[3] += __builtin_amdgcn_cvt_f32_fp8(v, 3) * w;
}

// ---- weight prep + degi zero + gcur zero (fused) ----
__global__ __launch_bounds__(256) void prep_kernel(
    const float* __restrict__ w_hid, const float* __restrict__ W_a1,
    const float* __restrict__ gcn1,  const float* __restrict__ w2,
    const float* __restrict__ W_a2,  const float* __restrict__ gcn2,
    const float* __restrict__ wfc,   float* __restrict__ ws)
{
    int j = blockIdx.x * 256 + threadIdx.x;
    if (j < 32768) { ((u16*)(ws+O_WHB))[j] = f2bf(w_hid[j]); return; } j -= 32768;
    if (j < 16384) { int r=j>>7, c=j&127; ((u16*)(ws+O_G1TB))[j] = f2bf(gcn1[c*128+r]); return; } j -= 16384;
    if (j < 16384) { int r=j>>7, c=j&127;
                     ((u16*)(ws+O_AW1B))[j] = f2bf(W_a1[r*128+c] - W_a1[c*128+r] - (r==c?GAMMAC:0.f));
                     return; } j -= 16384;
    if (j < 8192)  { ((u16*)(ws+O_W2B))[j] = f2bf(w2[j]); return; } j -= 8192;
    if (j < 4096)  { int r=j>>6, c=j&63;
                     ((u16*)(ws+O_AW2B))[j] = f2bf(W_a2[r*64+c] - W_a2[c*64+r] - (r==c?GAMMAC:0.f));
                     return; } j -= 4096;
    if (j < 4096)  { int r=j>>6, c=j&63; ((u16*)(ws+O_G2TB))[j] = f2bf(gcn2[c*64+r]); return; } j -= 4096;
    if (j < 2560)  { ((u16*)(ws+O_WFCB))[j] = f2bf(wfc[j]); return; } j -= 2560;
    if (j < NNODE) { ((int*)(ws+O_DEGI))[j] = 0; return; } j -= NNODE;
    if (j == 0)    { ((int*)(ws+O_GCUR))[0] = 0; }
}

// ---- CSR build (deg_count merged into x-GEMM kernel below) ----
__global__ __launch_bounds__(256) void alloc_kernel(const int* __restrict__ degi,
                                                    float* __restrict__ dinv,
                                                    int* __restrict__ rowptr,
                                                    int* __restrict__ cursor,
                                                    int* __restrict__ gcur) {
    int i = blockIdx.x * 256 + threadIdx.x;
    if (i >= NNODE) return;
    int d = degi[i];
    dinv[i] = rsqrtf(1.0f + (float)d);   // +1 self loop
    int pos = atomicAdd(gcur, d);
    rowptr[i] = pos;
    cursor[i] = pos;
}
__global__ __launch_bounds__(256) void fill_kernel(const int* __restrict__ ei,
                                                   const float* __restrict__ dinv,
                                                   int* __restrict__ cursor,
                                                   int2* __restrict__ ecsr) {
    int e = blockIdx.x * 256 + threadIdx.x;
    if (e >= NEDGE) return;
    int s = ei[e], d = ei[NEDGE + e];
    int pos = atomicAdd(&cursor[d], 1);
    int2 v;
    v.x = s;
    v.y = __float_as_int(dinv[s] * dinv[d]);
    ecsr[pos] = v;
}

// ---- MFMA GEMM (single-B): x @ w_hid^T, EPI=1; blocks >= NTILE do deg-count ----
template<int KS, int NT, int AF32, int LOADACT, int EPI>
__global__ __launch_bounds__(256, 4) void mgemm(
    const void* __restrict__ Araw,
    const u16* __restrict__ Bt,
    const float* __restrict__ bias,
    float* __restrict__ outF,
    u16* __restrict__ outB,
    u16* __restrict__ outB8,
    int M, int Nn, int ldc,
    const int* __restrict__ ei,      // edge dst for deg-count (may be null)
    int* __restrict__ degi)          // deg accumulator (may be null)
{
    // deg-count blocks: independent of GEMM work (GEMM never touches degi)
    if (ei && blockIdx.x >= NTILE) {
        for (int e = (blockIdx.x - NTILE) * 256 + threadIdx.x; e < NEDGE; e += XDEG * 256)
            atomicAdd(&degi[ei[NEDGE + e]], 1);
        return;
    }

    constexpr int K    = KS * 32;
    constexpr int KCHU = (K > 128) ? 128 : K;
    constexpr int KC   = KCHU / 32;
    constexpr int NCH  = K / KCHU;
    constexpr int P    = KCHU + 8;
    constexpr int ROWS = NT * 16;
    constexpr int CW   = NT * 16 + 1;
    constexpr int BSZ  = ROWS * P * 2;
    constexpr int ASZ  = 64 * CW * 4;
    constexpr int SMEM = BSZ > ASZ ? BSZ : ASZ;
    __shared__ __align__(16) char smem[SMEM];
    u16*   bl   = (u16*)smem;
    float* accL = (float*)smem;

    const int wave = threadIdx.x >> 6;
    const int lane = threadIdx.x & 63;
    const int m = lane & 15, q = lane >> 4;
    const int rowbase = blockIdx.x * 64 + wave * 16;
    const int row = rowbase + m;
    const bool rok = row < M;
    const short8 z8 = {0,0,0,0,0,0,0,0};

    short8 af[KS];
    if (AF32) {
        const float* apf = (const float*)Araw + (long long)row * K;
        #pragma unroll
        for (int k = 0; k < KS; ++k) {
            short8 t = z8;
            if (rok) {
                const float4* p = (const float4*)(apf + (k * 4 + q) * 8);
                float4 a = p[0], b = p[1];
                t[0]=(short)f2bf(a.x); t[1]=(short)f2bf(a.y); t[2]=(short)f2bf(a.z); t[3]=(short)f2bf(a.w);
                t[4]=(short)f2bf(b.x); t[5]=(short)f2bf(b.y); t[6]=(short)f2bf(b.z); t[7]=(short)f2bf(b.w);
            }
            af[k] = t;
        }
    } else {
        const short8* ap = (const short8*)((const u16*)Araw + (long long)row * K);
        #pragma unroll
        for (int k = 0; k < KS; ++k) af[k] = rok ? ap[k * 4 + q] : z8;
    }
    if (LOADACT) {
        #pragma unroll
        for (int k = 0; k < KS; ++k)
            #pragma unroll
            for (int e = 0; e < 8; ++e) {
                float f = bf2f((u16)af[k][e]);
                f = f > 0.f ? f : 0.01f * f;
                af[k][e] = (short)f2bf(f);
            }
    }

    f32x4 acc[NT];
    #pragma unroll
    for (int j = 0; j < NT; ++j) acc[j] = (f32x4){0.f,0.f,0.f,0.f};

    for (int ch = 0; ch < NCH; ++ch) {
        if (ch) __syncthreads();
        constexpr int CHUNKS = ROWS * (KCHU / 8);
        for (int t = threadIdx.x; t < CHUNKS; t += 256) {
            int r = t / (KCHU / 8), c = t - r * (KCHU / 8);
            short8 v = z8;
            if (r < Nn) v = *(const short8*)&Bt[(long long)r * K + ch * KCHU + c * 8];
            *(short8*)&bl[r * P + c * 8] = v;
        }
        __syncthreads();
        #pragma unroll
        for (int j = 0; j < NT; ++j) {
            #pragma unroll
            for (int k = 0; k < KC; ++k) {
                short8 bf_ = *(const short8*)&bl[(j * 16 + m) * P + k * 32 + q * 8];
                acc[j] = __builtin_amdgcn_mfma_f32_16x16x32_bf16(af[ch * KC + k], bf_, acc[j], 0, 0, 0);
            }
        }
    }

    __syncthreads();
    #pragma unroll
    for (int j = 0; j < NT; ++j)
        #pragma unroll
        for (int r = 0; r < 4; ++r)
            accL[(wave * 16 + q * 4 + r) * CW + j * 16 + m] = acc[j][r];
    __syncthreads();

    const int c0 = lane * 2;
    if (c0 < NT * 16) {
        float2 bv = {0.f, 0.f};
        if (bias) {
            if (c0 < Nn)     bv.x = bias[c0];
            if (c0 + 1 < Nn) bv.y = bias[c0 + 1];
        }
        #pragma unroll
        for (int rl = 0; rl < 16; ++rl) {
            int rowD = rowbase + rl;
            if (rowD >= M) continue;
            float2 v = *(const float2*)&accL[(wave * 16 + rl) * CW + c0];
            long long o = (long long)rowD * ldc + c0;
            v.x += bv.x; v.y += bv.y;
            if (EPI == 1) {
                v.x = v.x > 0.f ? v.x : 0.01f * v.x;
                v.y = v.y > 0.f ? v.y : 0.01f * v.y;
            }
            if (c0 + 1 < Nn) {
                if (outB) { ushort2 ob; ob.x = f2bf(v.x); ob.y = f2bf(v.y);
                            *(ushort2*)&outB[o] = ob; }
                if (outB8) outB8[o >> 1] = pk_fp8(v.x, v.y);
                if (outF) { *(float2*)&outF[o] = v; }
            } else if (c0 < Nn) {
                if (outB) outB[o] = f2bf(v.x);
                if (outF) outF[o] = v.x;
            }
        }
    }
}

// ---- standalone CSR gather (fp8 in, bf16 out): agg = Â h (wave per node) ----
// inner loop 4-unrolled (16 edges/batch): 4 independent row loads in flight
template<int HD>
__global__ __launch_bounds__(256) void gather_kernel(
    const int* __restrict__ rowptr, const int* __restrict__ degi,
    const int2* __restrict__ ecsr, const float* __restrict__ dinv,
    const u32* __restrict__ g8, u16* __restrict__ aggB)
{
    int node = (blockIdx.x * 256 + threadIdx.x) >> 6;
    int lane = threadIdx.x & 63;
    if (node >= NNODE) return;
    const int qr = lane >> 4, l4 = lane & 15;
    const int r0 = rowptr[node];
    const int r1 = r0 + degi[node];
    const float wself = dinv[node] * dinv[node];
    constexpr int EL = (HD == 128) ? 8 : 4;

    float a[EL];
    #pragma unroll
    for (int i = 0; i < EL; ++i) a[i] = 0.f;
    if (qr == 0) {
        if (HD == 128) {
            uint2 gv = ((const uint2*)g8)[(long long)node * 16 + l4];
            acc_fp8x4(a, gv.x, wself);
            acc_fp8x4(a + 4, gv.y, wself);
        } else {
            u32 gv = g8[(long long)node * 16 + l4];
            acc_fp8x4(a, gv, wself);
        }
    }

    for (int base = r0; base < r1; base += 64) {
        int idx = base + lane;
        int cs = 0; float cw = 0.f;
        if (idx < r1) { int2 ev = ecsr[idx]; cs = ev.x; cw = __int_as_float(ev.y); }
        int cnt = min(64, r1 - base);
        for (int j = 0; j < cnt; j += 16) {
            #pragma unroll
            for (int u = 0; u < 4; ++u) {
                int jj = j + u * 4 + qr;            // lanes past cnt carry cw=0
                int   s = __shfl(cs, jj);
                float w = __shfl(cw, jj);
                if (HD == 128) {
                    uint2 gv = ((const uint2*)g8)[(long long)s * 16 + l4];
                    acc_fp8x4(a, gv.x, w);
                    acc_fp8x4(a + 4, gv.y, w);
                } else {
                    u32 gv = g8[(long long)s * 16 + l4];
                    acc_fp8x4(a, gv, w);
                }
            }
        }
    }

    #pragma unroll
    for (int i = 0; i < EL; ++i) {
        a[i] += __shfl_xor(a[i], 16);
        a[i] += __shfl_xor(a[i], 32);
    }
    if (HD == 128) {
        float v0 = (qr == 0) ? a[0] : (qr == 1) ? a[2] : (qr == 2) ? a[4] : a[6];
        float v1 = (qr == 0) ? a[1] : (qr == 1) ? a[3] : (qr == 2) ? a[5] : a[7];
        long long o = (long long)node * 128 + l4 * 8 + qr * 2;
        ushort2 ob; ob.x = f2bf(v0); ob.y = f2bf(v1);
        *(ushort2*)&aggB[o] = ob;
    } else {
        float v = (qr == 0) ? a[0] : (qr == 1) ? a[1] : (qr == 2) ? a[2] : a[3];
        aggB[(long long)node * 64 + l4 * 4 + qr] = f2bf(v);
    }
}

// ---- conv-step GEMM: acc = h@aW^T + (Âh)@G, epi h+eps*tanh(acc+b) ----
// TAIL=0: write h_new (bf16) + fp8 shadow.
// TAIL=1: additionally fuse h2 = leaky(leaky(h_new)@w2^T + b2); only h2 (+shadow) hits HBM.
template<int KS, int NT, int TAIL>
__global__ __launch_bounds__(256, TAIL ? 3 : 4) void mgemm_conv(
    const u16* __restrict__ hA,      // h  [M,K] bf16
    const u16* __restrict__ gA,      // Âh [M,K] bf16
    const u16* __restrict__ BtW,
    const u16* __restrict__ BtG,
    const float* __restrict__ bias,
    u16* __restrict__ outB,
    u16* __restrict__ outB8,         // fp8 shadow of output, may be null
    const u16* __restrict__ w2W,     // TAIL only: w2 [64,128] bf16
    const float* __restrict__ b2,    // TAIL only
    int M)
{
    constexpr int K    = KS * 32;
    constexpr int Nn   = NT * 16;
    constexpr int P    = K + 8;
    constexpr int CW   = Nn + 1;
    constexpr int BSZ  = Nn * P * 2;
    constexpr int ASZ  = 64 * CW * 4;
    constexpr int R1   = BSZ > ASZ ? BSZ : ASZ;
    constexpr int EXTRA = TAIL ? 64 * P * 2 : 0;
    __shared__ __align__(16) char smem[R1 + EXTRA];
    u16*   bl   = (u16*)smem;
    float* accL = (float*)smem;
    u16*   aggT = (u16*)(smem + R1);   // TAIL: leaky(h_new) tile

    const int wave = threadIdx.x >> 6;
    const int lane = threadIdx.x & 63;
    const int m = lane & 15, q = lane >> 4;
    const int rowbase = blockIdx.x * 64 + wave * 16;
    const int row = rowbase + m;
    const bool rok = row < M;
    const short8 z8 = {0,0,0,0,0,0,0,0};

    short8 af1[KS], af2[KS];
    {
        const short8* ap1 = (const short8*)(hA + (long long)row * K);
        const short8* ap2 = (const short8*)(gA + (long long)row * K);
        #pragma unroll
        for (int k = 0; k < KS; ++k) {
            af1[k] = rok ? ap1[k * 4 + q] : z8;
            af2[k] = rok ? ap2[k * 4 + q] : z8;
        }
    }

    f32x4 acc[NT];
    #pragma unroll
    for (int j = 0; j < NT; ++j) acc[j] = (f32x4){0.f,0.f,0.f,0.f};

    #pragma unroll
    for (int pass = 0; pass < 2; ++pass) {
        const u16* Bcur = pass ? BtG : BtW;
        if (pass) __syncthreads();
        constexpr int CHUNKS = Nn * (K / 8);
        for (int t = threadIdx.x; t < CHUNKS; t += 256) {
            int r = t / (K / 8), c = t - r * (K / 8);
            *(short8*)&bl[r * P + c * 8] = *(const short8*)&Bcur[(long long)r * K + c * 8];
        }
        __syncthreads();
        #pragma unroll
        for (int j = 0; j < NT; ++j) {
            #pragma unroll
            for (int k = 0; k < KS; ++k) {
                short8 bf_ = *(const short8*)&bl[(j * 16 + m) * P + k * 32 + q * 8];
                acc[j] = __builtin_amdgcn_mfma_f32_16x16x32_bf16(
                    pass ? af2[k] : af1[k], bf_, acc[j], 0, 0, 0);
            }
        }
    }

    __syncthreads();
    #pragma unroll
    for (int j = 0; j < NT; ++j)
        #pragma unroll
        for (int r = 0; r < 4; ++r)
            accL[(wave * 16 + q * 4 + r) * CW + j * 16 + m] = acc[j][r];
    __syncthreads();

    const int c0 = lane * 2;
    if (TAIL == 0) {
        if (c0 < Nn) {
            float2 bv = {bias[c0], bias[c0 + 1]};
            #pragma unroll
            for (int rl = 0; rl < 16; ++rl) {
                int rowD = rowbase + rl;
                if (rowD >= M) continue;
                float2 v = *(const float2*)&accL[(wave * 16 + rl) * CW + c0];
                long long o = (long long)rowD * Nn + c0;
                ushort2 hh = *(const ushort2*)&hA[o];
                float n0 = bf2f(hh.x) + EPSC * ftanh(v.x + bv.x);
                float n1 = bf2f(hh.y) + EPSC * ftanh(v.y + bv.y);
                ushort2 ob; ob.x = f2bf(n0); ob.y = f2bf(n1);
                *(ushort2*)&outB[o] = ob;
                if (outB8) outB8[o >> 1] = pk_fp8(n0, n1);
            }
        }
        return;
    }

    // ---- TAIL=1: leaky(h_new) -> LDS tile, then h2 = leaky(tile @ w2^T + b2) ----
    {
        float2 bv = {bias[c0], bias[c0 + 1]};
        #pragma unroll
        for (int rl = 0; rl < 16; ++rl) {
            int rowD = rowbase + rl;
            float n0 = 0.f, n1 = 0.f;
            if (rowD < M) {
                float2 v = *(const float2*)&accL[(wave * 16 + rl) * CW + c0];
                long long o = (long long)rowD * K + c0;
                ushort2 hh = *(const ushort2*)&hA[o];
                n0 = bf2f(hh.x) + EPSC * ftanh(v.x + bv.x);
                n1 = bf2f(hh.y) + EPSC * ftanh(v.y + bv.y);
                n0 = n0 > 0.f ? n0 : 0.01f * n0;
                n1 = n1 > 0.f ? n1 : 0.01f * n1;
            }
            ushort2 ob; ob.x = f2bf(n0); ob.y = f2bf(n1);
            *(ushort2*)&aggT[(wave * 16 + rl) * P + c0] = ob;
        }
    }
    __syncthreads();     // accL region about to be overwritten by w2 stage

    short8 af3[4];
    #pragma unroll
    for (int k = 0; k < 4; ++k)
        af3[k] = *(const short8*)&aggT[(wave * 16 + m) * P + k * 32 + q * 8];

    // stage w2 [64,128]
    {
        constexpr int CH2 = 64 * 16;
        for (int t = threadIdx.x; t < CH2; t += 256) {
            int r = t >> 4, c = t & 15;
            *(short8*)&bl[r * P + c * 8] = *(const short8*)&w2W[(long long)r * K + c * 8];
        }
    }
    __syncthreads();

    f32x4 acc2[4];
    #pragma unroll
    for (int j = 0; j < 4; ++j) acc2[j] = (f32x4){0.f,0.f,0.f,0.f};
    #pragma unroll
    for (int j = 0; j < 4; ++j)
        #pragma unroll
        for (int k = 0; k < 4; ++k) {
            short8 bf_ = *(const short8*)&bl[(j * 16 + m) * P + k * 32 + q * 8];
            acc2[j] = __builtin_amdgcn_mfma_f32_16x16x32_bf16(af3[k], bf_, acc2[j], 0, 0, 0);
        }

    __syncthreads();
    constexpr int CW2 = 65;
    #pragma unroll
    for (int j = 0; j < 4; ++j)
        #pragma unroll
        for (int r = 0; r < 4; ++r)
            accL[(wave * 16 + q * 4 + r) * CW2 + j * 16 + m] = acc2[j][r];
    __syncthreads();

    if (c0 < 64) {
        float2 bv = {b2[c0], b2[c0 + 1]};
        #pragma unroll
        for (int rl = 0; rl < 16; ++rl) {
            int rowD = rowbase + rl;
            if (rowD >= M) continue;
            float2 v = *(const float2*)&accL[(wave * 16 + rl) * CW2 + c0];
            v.x += bv.x; v.y += bv.y;
            v.x = v.x > 0.f ? v.x : 0.01f * v.x;
            v.y = v.y > 0.f ? v.y : 0.01f * v.y;
            long long o = (long long)rowD * 64 + c0;
            ushort2 ob; ob.x = f2bf(v.x); ob.y = f2bf(v.y);
            *(ushort2*)&outB[o] = ob;
            outB8[o >> 1] = pk_fp8(v.x, v.y);
        }
    }
}

// ---- fused conv2 + FC + log_softmax (agg from global) ----
__global__ __launch_bounds__(256, 4) void conv2fc(
    const u16* __restrict__ hA,      // h2 [M,64] bf16
    const u16* __restrict__ gA,      // Âh2 [M,64] bf16 (from gather<64>)
    const u16* __restrict__ BtW, const u16* __restrict__ BtG,
    const float* __restrict__ bias,
    const u16* __restrict__ wfcB, const float* __restrict__ bfc,
    float* __restrict__ outF, int M)
{
    constexpr int K  = 64, NT = 4, KS = 2;
    constexpr int P  = K + 8;                 // 72
    constexpr int CW = 65;
    constexpr int R1 = 64 * CW * 4;           // 16640 (max phase use of region 1)
    __shared__ __align__(16) char smem[R1 + 64 * P * 2];   // +9216 h2n tile
    u16*   bl   = (u16*)smem;
    float* accL = (float*)smem;
    u16*   aggT = (u16*)(smem + R1);

    const int wave = threadIdx.x >> 6;
    const int lane = threadIdx.x & 63;
    const int m = lane & 15, q = lane >> 4;
    const int rowbase = blockIdx.x * 64 + wave * 16;
    const int row = rowbase + m;
    const bool rok = row < M;
    const short8 z8 = {0,0,0,0,0,0,0,0};

    short8 af1[KS], af2[KS];
    {
        const short8* ap1 = (const short8*)(hA + (long long)row * K);
        const short8* ap2 = (const short8*)(gA + (long long)row * K);
        #pragma unroll
        for (int k = 0; k < KS; ++k) {
            af1[k] = rok ? ap1[k * 4 + q] : z8;
            af2[k] = rok ? ap2[k * 4 + q] : z8;
        }
    }

    f32x4 acc[NT];
    #pragma unroll
    for (int j = 0; j < NT; ++j) acc[j] = (f32x4){0.f,0.f,0.f,0.f};

    #pragma unroll
    for (int pass = 0; pass < 2; ++pass) {
        const u16* Bcur = pass ? BtG : BtW;
        if (pass) __syncthreads();
        constexpr int CHUNKS = 64 * (K / 8);      // 512
        for (int t = threadIdx.x; t < CHUNKS; t += 256) {
            int r = t >> 3, c = t & 7;
            *(short8*)&bl[r * P + c * 8] = *(const short8*)&Bcur[(long long)r * K + c * 8];
        }
        __syncthreads();
        #pragma unroll
        for (int j = 0; j < NT; ++j)
            #pragma unroll
            for (int k = 0; k < KS; ++k) {
                short8 bf_ = *(const short8*)&bl[(j * 16 + m) * P + k * 32 + q * 8];
                acc[j] = __builtin_amdgcn_mfma_f32_16x16x32_bf16(
                    pass ? af2[k] : af1[k], bf_, acc[j], 0, 0, 0);
            }
    }

    __syncthreads();
    #pragma unroll
    for (int j = 0; j < NT; ++j)
        #pragma unroll
        for (int r = 0; r < 4; ++r)
            accL[(wave * 16 + q * 4 + r) * CW + j * 16 + m] = acc[j][r];
    __syncthreads();

    // epilogue1: h2n = h2 + eps*tanh(acc + b_a2) -> aggT tile
    {
        const int c0 = lane * 2;
        float2 bv = {bias[c0 & 63], bias[(c0 + 1) & 63]};
        if (c0 < 64) {
            #pragma unroll
            for (int rl = 0; rl < 16; ++rl) {
                int rowD = rowbase + rl;
                float n0 = 0.f, n1 = 0.f;
                if (rowD < M) {
                    float2 v = *(const float2*)&accL[(wave * 16 + rl) * CW + c0];
                    long long o = (long long)rowD * 64 + c0;
                    ushort2 hh = *(const ushort2*)&hA[o];
                    n0 = bf2f(hh.x) + EPSC * ftanh(v.x + bv.x);
                    n1 = bf2f(hh.y) + EPSC * ftanh(v.y + bv.y);
                }
                ushort2 ob; ob.x = f2bf(n0); ob.y = f2bf(n1);
                *(ushort2*)&aggT[(wave * 16 + rl) * P + c0] = ob;
            }
        }
    }
    __syncthreads();   // accL region about to be restaged with wfc

    short8 af4[KS];
    #pragma unroll
    for (int k = 0; k < KS; ++k)
        af4[k] = *(const short8*)&aggT[(wave * 16 + m) * P + k * 32 + q * 8];

    // stage wfc [40,64], zero-pad rows 40..47 (NT=3 -> 48 rows)
    {
        constexpr int CHF = 48 * 8;
        for (int t = threadIdx.x; t < CHF; t += 256) {
            int r = t >> 3, c = t & 7;
            short8 v = z8;
            if (r < 40) v = *(const short8*)&wfcB[(long long)r * K + c * 8];
            *(short8*)&bl[r * P + c * 8] = v;
        }
    }
    __syncthreads();

    f32x4 acc3[3];
    #pragma unroll
    for (int j = 0; j < 3; ++j) acc3[j] = (f32x4){0.f,0.f,0.f,0.f};
    #pragma unroll
    for (int j = 0; j < 3; ++j)
        #pragma unroll
        for (int k = 0; k < KS; ++k) {
            short8 bf_ = *(const short8*)&bl[(j * 16 + m) * P + k * 32 + q * 8];
            acc3[j] = __builtin_amdgcn_mfma_f32_16x16x32_bf16(af4[k], bf_, acc3[j], 0, 0, 0);
        }

    __syncthreads();
    constexpr int CW3 = 49;
    #pragma unroll
    for (int j = 0; j < 3; ++j)
        #pragma unroll
        for (int r = 0; r < 4; ++r)
            accL[(wave * 16 + q * 4 + r) * CW3 + j * 16 + m] = acc3[j][r];
    __syncthreads();

    // fused log_softmax over 40 cols
    float mrow = 0.f, lrow = 0.f;
    if (lane < 16) {
        const float* rp = &accL[(wave * 16 + lane) * CW3];
        float mx = -1e30f;
        for (int c = 0; c < 40; ++c) mx = fmaxf(mx, rp[c] + bfc[c]);
        float s = 0.f;
        for (int c = 0; c < 40; ++c) s += expf(rp[c] + bfc[c] - mx);
        mrow = mx; lrow = logf(s);
    }
    for (int rl = 0; rl < 16; ++rl) {
        float mm = __shfl(mrow, rl);
        float ll = __shfl(lrow, rl);
        int rowD = rowbase + rl;
        if (rowD < M && lane < 40) {
            float v = accL[(wave * 16 + rl) * CW3 + lane] + bfc[lane];
            outF[(long long)rowD * 40 + lane] = v - mm - ll;
        }
    }
}

extern "C" void kernel_launch(void* const* d_in, const int* in_sizes, int n_in,
                              void* d_out, int out_size, void* d_ws, size_t ws_size,
                              hipStream_t stream) {
    const float* x     = (const float*)d_in[0];
    const int*   ei    = (const int*)d_in[1];
    const float* w_hid = (const float*)d_in[2];
    const float* b_hid = (const float*)d_in[3];
    const float* W_a1  = (const float*)d_in[4];
    const float* gcn1  = (const float*)d_in[5];
    const float* b_a1  = (const float*)d_in[6];
    const float* w2    = (const float*)d_in[7];
    const float* b2    = (const float*)d_in[8];
    const float* W_a2  = (const float*)d_in[9];
    const float* gcn2  = (const float*)d_in[10];
    const float* b_a2  = (const float*)d_in[11];
    const float* wfc   = (const float*)d_in[12];
    const float* bfc   = (const float*)d_in[13];
    float* ws = (float*)d_ws;
    float* out = (float*)d_out;

    float* dinv   = ws + O_DINV;
    int*   degi   = (int*)(ws + O_DEGI);
    int*   rowptr = (int*)(ws + O_ROWPTR);
    int*   cursor = (int*)(ws + O_CURSOR);
    int*   gcur   = (int*)(ws + O_GCUR);
    int2*  ecsr   = (int2*)(ws + O_ECSR);
    u16* whB  = (u16*)(ws + O_WHB);
    u16* g1tB = (u16*)(ws + O_G1TB);
    u16* aw1B = (u16*)(ws + O_AW1B);
    u16* w2B  = (u16*)(ws + O_W2B);
    u16* aw2B = (u16*)(ws + O_AW2B);
    u16* g2tB = (u16*)(ws + O_G2TB);
    u16* wfcB = (u16*)(ws + O_WFCB);
    u16* aggB = (u16*)(ws + O_AGGB);
    u16* hB0  = (u16*)(ws + O_HB0);
    u16* hB1  = (u16*)(ws + O_HB1);
    u16* s0   = (u16*)(ws + O_S0);
    u16* s1   = (u16*)(ws + O_S1);

    const int nNodeB = (NNODE + 255) / 256;

    prep_kernel<<<(84480 + NNODE + 256 + 255) / 256, 256, 0, stream>>>(
        w_hid, W_a1, gcn1, w2, W_a2, gcn2, wfc, ws);

    const int gatherBlocks = (NNODE * 64 + 255) / 256;   // 12500 (wave per node)

    // h = leaky_relu(x @ w_hid^T + b_hid) -> hB0 (+fp8 shadow s0);
    // blocks >= NTILE concurrently count edge degrees (deg_count merged)
    mgemm<8, 8, 1, 0, 1><<<NTILE + XDEG, 256, 0, stream>>>(
        x, whB, b_hid, nullptr, hB0, s0, NNODE, 128, 128, ei, degi);

    alloc_kernel<<<nNodeB, 256, 0, stream>>>(degi, dinv, rowptr, cursor, gcur);
    fill_kernel<<<(NEDGE + 255) / 256, 256, 0, stream>>>(ei, dinv, cursor, ecsr);

    // conv1 iter1
    gather_kernel<128><<<gatherBlocks, 256, 0, stream>>>(
        rowptr, degi, ecsr, dinv, (const u32*)s0, aggB);
    mgemm_conv<4, 8, 0><<<NTILE, 256, 0, stream>>>(
        hB0, aggB, aw1B, g1tB, b_a1, hB1, s1, nullptr, nullptr, NNODE);
    // conv1 iter2
    gather_kernel<128><<<gatherBlocks, 256, 0, stream>>>(
        rowptr, degi, ecsr, dinv, (const u32*)s1, aggB);
    mgemm_conv<4, 8, 0><<<NTILE, 256, 0, stream>>>(
        hB1, aggB, aw1B, g1tB, b_a1, hB0, s0, nullptr, nullptr, NNODE);
    // conv1 iter3 + fused h2 = leaky(leaky(h_new)@w2^T + b2) -> hB1 (+shadow s1)
    gather_kernel<128><<<gatherBlocks, 256, 0, stream>>>(
        rowptr, degi, ecsr, dinv, (const u32*)s0, aggB);
    mgemm_conv<4, 8, 1><<<NTILE, 256, 0, stream>>>(
        hB0, aggB, aw1B, g1tB, b_a1, hB1, s1, w2B, b2, NNODE);

    // conv2 + fc + log_softmax (gather stays standalone for TLP)
    gather_kernel<64><<<gatherBlocks, 256, 0, stream>>>(
        rowptr, degi, ecsr, dinv, (const u32*)s1, aggB);
    conv2fc<<<NTILE, 256, 0, stream>>>(
        hB1, aggB, aw2B, g2tB, b_a2, wfcB, bfc, out, NNODE);
}